// Round 3
// baseline (235.730 us; speedup 1.0000x reference)
//
#include <hip/hip_runtime.h>
#include <math.h>

// VQ-VAE VectorQuantizer forward for MI355X (gfx950).
// x: [B=32, C=64, H=32, W=32] f32, codebook: [K=1024, D=64] f32
// d_out (f32): quantized[2097152] | vq_loss[1] | indices[32768]
//
// fp32 distance "GEMM" (no fp32 MFMA on CDNA4) -> VALU-bound floor ~27us.
// A-fragment (x tile) from LDS, B-fragment (codebook) from GLOBAL via a
// pre-transposed cbT[d][k] panel (L1/L2-resident, 512B/d-row per pass) so
// LDS and L1 pipes split operand traffic and VALU is the only saturated
// pipe. 8x8 register tile per thread.
//
// Rounding mimics the reference exactly where it matters for argmin:
//   dist = fl( fl(x2 + cb2) - 2*dot ), norms square-then-add sequential-d,
//   dot = sequential-d fma, 2*dot exact (power of two), strict-< argmin
//   with ascending k => first-index tie-break (jnp.argmin semantics).

#define NB   32
#define ND   64
#define NHW  1024
#define NK   1024
#define TM   128         // positions per block
#define TPB  256
#define MT   8           // m per thread
#define KT   8           // k per thread
#define KTILE 128        // k per pass (16 kgroups * 8)
#define NPASS (NK / KTILE)
#define QELEMS (NB * ND * NHW)   // 2097152
#define FBIG 3.402823466e38f

typedef float f4 __attribute__((ext_vector_type(4)));

// ---------- prep: codebook norms, transpose cbT[d][k], zero loss acc ----------
__global__ void vq_prep(const float* __restrict__ cb, float* __restrict__ cb2,
                        float* __restrict__ cbT, double* __restrict__ lacc) {
    int i = blockIdx.x * blockDim.x + threadIdx.x;   // 0..65535
    if (i == 0) *lacc = 0.0;
    if (i < NK) {
        float s = 0.f;
        #pragma unroll 8
        for (int d = 0; d < ND; ++d) {
            float v = cb[i * ND + d];
            s = __fadd_rn(s, __fmul_rn(v, v));       // square-then-add (sum(cb**2))
        }
        cb2[i] = s;
    }
    int d = i >> 10, k = i & 1023;
    cbT[d * NK + k] = cb[k * ND + d];
}

// ---------- main: distances + argmin + gather + STE + loss ----------
__global__ __launch_bounds__(TPB, 2)   // cap 256 VGPR; >=8 waves/CU
void vq_main(const float* __restrict__ x, const float* __restrict__ cb,
             const float* __restrict__ cbT, const float* __restrict__ cb2g,
             float* __restrict__ outq, float* __restrict__ outidx,
             double* __restrict__ lacc)
{
    __shared__ __align__(16) float xs[ND][TM];   // 32 KB
    __shared__ float x2s[TM];
    __shared__ float wbd[4][TM];                 // per-wave best dist
    __shared__ int   wbi[4][TM];
    __shared__ int   fidx[TM];
    __shared__ float redv[4];

    const int tid = threadIdx.x;
    const int blk = blockIdx.x;
    const int b   = blk >> 3;              // 32 batches
    const int hw0 = (blk & 7) * TM;        // 8 tiles of 128 positions
    const float* xb = x + b * (ND * NHW) + hw0;

    // stage x tile (coalesced over m)
    #pragma unroll
    for (int i = tid; i < ND * TM; i += TPB) {
        int d = i >> 7, m = i & 127;
        xs[d][m] = xb[d * NHW + m];
    }
    __syncthreads();

    // ||x||^2 per position: sequential d, square-then-add (mimic reference)
    if (tid < TM) {
        float s = 0.f;
        #pragma unroll 8
        for (int d = 0; d < ND; ++d) {
            float v = xs[d][tid];
            s = __fadd_rn(s, __fmul_rn(v, v));
        }
        x2s[tid] = s;
    }
    __syncthreads();

    const int mg = tid & 15;     // m-group: positions m0..m0+7
    const int kg = tid >> 4;     // k-group within pass
    const int m0 = mg * MT;

    float x2loc[MT];
    #pragma unroll
    for (int j = 0; j < MT; ++j) x2loc[j] = x2s[m0 + j];

    float bd[MT];
    int   bi[MT];
    #pragma unroll
    for (int j = 0; j < MT; ++j) { bd[j] = FBIG; bi[j] = 0; }

    for (int pass = 0; pass < NPASS; ++pass) {
        const int k0 = pass * KTILE + kg * KT;
        float acc[MT][KT];
        #pragma unroll
        for (int j = 0; j < MT; ++j)
            #pragma unroll
            for (int jj = 0; jj < KT; ++jj) acc[j][jj] = 0.f;

        const float* bp = cbT + k0;
        #pragma unroll 4
        for (int d = 0; d < ND; ++d) {
            f4 a0 = *reinterpret_cast<const f4*>(&xs[d][m0]);      // LDS pipe
            f4 a1 = *reinterpret_cast<const f4*>(&xs[d][m0 + 4]);
            f4 b0 = *reinterpret_cast<const f4*>(&bp[d * NK]);     // L1 pipe
            f4 b1 = *reinterpret_cast<const f4*>(&bp[d * NK + 4]);
            #pragma unroll
            for (int j = 0; j < MT; ++j) {
                float av = (j < 4) ? a0[j & 3] : a1[j & 3];
                #pragma unroll
                for (int jj = 0; jj < KT; ++jj) {
                    float bv = (jj < 4) ? b0[jj & 3] : b1[jj & 3];
                    acc[j][jj] = fmaf(av, bv, acc[j][jj]);         // seq-d fma dot
                }
            }
        }

        // fold distances: dist = fl( fl(x2 + cb2) - 2*dot ), k ascending
        #pragma unroll
        for (int jj = 0; jj < KT; ++jj) {
            const int kgl = k0 + jj;
            const float c2 = cb2g[kgl];
            #pragma unroll
            for (int j = 0; j < MT; ++j) {
                float t    = __fadd_rn(x2loc[j], c2);
                float dist = __fsub_rn(t, 2.0f * acc[j][jj]);      // 2*dot exact
                if (dist < bd[j]) { bd[j] = dist; bi[j] = kgl; }   // strict <: first idx
            }
        }
    }

    // intra-wave reduce over the wave's 4 k-groups (lanes ^16, ^32), lexicographic
    #pragma unroll
    for (int off = 16; off <= 32; off <<= 1) {
        #pragma unroll
        for (int j = 0; j < MT; ++j) {
            float od = __shfl_xor(bd[j], off, 64);
            int   oi = __shfl_xor(bi[j], off, 64);
            if (od < bd[j] || (od == bd[j] && oi < bi[j])) { bd[j] = od; bi[j] = oi; }
        }
    }
    const int w = tid >> 6;
    if ((tid & 63) < 16) {
        #pragma unroll
        for (int j = 0; j < MT; ++j) { wbd[w][m0 + j] = bd[j]; wbi[w][m0 + j] = bi[j]; }
    }
    __syncthreads();

    // cross-wave reduce + index write
    if (tid < TM) {
        float bestd = wbd[0][tid];
        int   besti = wbi[0][tid];
        #pragma unroll
        for (int t = 1; t < 4; ++t) {
            float dv = wbd[t][tid];
            int   iv = wbi[t][tid];
            if (dv < bestd || (dv == bestd && iv < besti)) { bestd = dv; besti = iv; }
        }
        fidx[tid] = besti;
        outidx[b * NHW + hw0 + tid] = (float)besti;
    }
    __syncthreads();

    // epilogue: gather codebook row, STE out = fl(x + fl(q - x)), loss accum
    const int m  = tid & 127;
    const int ch = tid >> 7;                 // channel half: 0..1 (32 ch each)
    const int myk = fidx[m];
    const float* crow = cb + myk * ND + ch * 32;
    float* oq = outq + b * (ND * NHW) + hw0 + m + ch * 32 * NHW;
    float ll = 0.f;
    #pragma unroll
    for (int cc = 0; cc < 8; ++cc) {
        f4 v = *reinterpret_cast<const f4*>(&crow[cc * 4]);   // L2-hot gather
        #pragma unroll
        for (int j = 0; j < 4; ++j) {
            int c = ch * 32 + cc * 4 + j;
            float xv = xs[c][m];
            float xd = __fsub_rn(v[j], xv);
            oq[(cc * 4 + j) * NHW] = __fadd_rn(xv, xd);
            ll = fmaf(xd, xd, ll);
        }
    }
    #pragma unroll
    for (int off = 32; off > 0; off >>= 1) ll += __shfl_down(ll, off, 64);
    if ((tid & 63) == 0) redv[tid >> 6] = ll;
    __syncthreads();
    if (tid == 0) {
        double s = (double)redv[0] + (double)redv[1] + (double)redv[2] + (double)redv[3];
        atomicAdd(lacc, s);
    }
}

// ---------- finalize: L = mean((q-x)^2); vq_loss = L + 0.25*L ----------
// e_latent_loss == q_latent_loss numerically (same fp32 inputs/op), so
// vq_loss = L + 0.25*L with the reference's add/mul rounding.
__global__ void vq_fin(const double* __restrict__ lacc, float* __restrict__ outloss) {
    double a = *lacc;
    float L = (float)(a * (1.0 / (double)QELEMS));
    *outloss = __fadd_rn(L, __fmul_rn(0.25f, L));
}

extern "C" void kernel_launch(void* const* d_in, const int* in_sizes, int n_in,
                              void* d_out, int out_size, void* d_ws, size_t ws_size,
                              hipStream_t stream) {
    const float* x  = (const float*)d_in[0];
    const float* cb = (const float*)d_in[1];
    float* outq    = (float*)d_out;
    float* outloss = outq + QELEMS;
    float* outidx  = outq + QELEMS + 1;

    float*  cb2  = (float*)d_ws;                                  // 4 KB slot
    float*  cbT  = (float*)((char*)d_ws + 4096);                  // 256 KB
    double* lacc = (double*)((char*)d_ws + 4096 + NK * ND * 4);   // 8 B

    vq_prep<<<256, 256, 0, stream>>>(cb, cb2, cbT, lacc);
    vq_main<<<256, TPB, 0, stream>>>(x, cb, cbT, cb2, outq, outidx, lacc);
    vq_fin<<<1, 1, 0, stream>>>(lacc, outloss);
}

// Round 7
// 139.949 us; speedup vs baseline: 1.6844x; 1.6844x over previous
//
#include <hip/hip_runtime.h>
#include <math.h>

// VQ-VAE VectorQuantizer forward for MI355X (gfx950).
// x: [B=32, C=64, H=32, W=32] f32, codebook: [K=1024, D=64] f32
// d_out (f32): quantized[2097152] | vq_loss[1] | indices[32768]
//
// Round-3 bench (TM=128, grid 256): 178us, VALUBusy 20%, Occupancy 11% --
// 1 block/CU = 1 wave/SIMD, latency-bound. Fix: TM=32 -> 1024 blocks =
// 4 blocks/CU = 4 waves/SIMD; 4x8 per-thread tile. A from LDS (conflict-free:
// 8 mgroups x 16B span banks 0-31 exactly once), B from global cbT[d][k]
// panel (L1/L2-hot) so LDS+L1 split operand traffic; VALU is the only
// saturated pipe. fp32 FMA floor = 27.3us.
// Rounds 4-6: infra failures on the variant with a device-side completion-
// counter finalizer; reverted to the separate vq_fin launch (the only
// structure that has passed the harness) -- boring beats clever here.
//
// Numerics (bit-exact in round 3 -- do not touch):
//   dist = fl( fl(x2 + cb2) - 2*dot ), norms square-then-add sequential-d,
//   dot = sequential-d fma, 2*dot exact, strict-< argmin ascending k,
//   lexicographic cross-lane tie-break => jnp.argmin first-index semantics.

#define NB   32
#define ND   64
#define NHW  1024
#define NK   1024
#define TM   32          // positions per block
#define TPB  256
#define MT   4           // m per thread
#define KT   8           // k per thread
#define KTILE 256        // k per pass (32 kgroups * 8)
#define NPASS (NK / KTILE)
#define NBLK (NB * NHW / TM)     // 1024 blocks
#define QELEMS (NB * ND * NHW)   // 2097152
#define FBIG 3.402823466e38f

typedef float f4 __attribute__((ext_vector_type(4)));

// ---------- prep: codebook norms, transpose cbT[d][k], zero loss acc ----------
__global__ void vq_prep(const float* __restrict__ cb, float* __restrict__ cb2,
                        float* __restrict__ cbT, double* __restrict__ lacc) {
    int i = blockIdx.x * blockDim.x + threadIdx.x;   // 0..65535
    if (i == 0) *lacc = 0.0;
    if (i < NK) {
        float s = 0.f;
        #pragma unroll 8
        for (int d = 0; d < ND; ++d) {
            float v = cb[i * ND + d];
            s = __fadd_rn(s, __fmul_rn(v, v));       // square-then-add (sum(cb**2))
        }
        cb2[i] = s;
    }
    int d = i >> 10, k = i & 1023;
    cbT[d * NK + k] = cb[k * ND + d];
}

// ---------- main: distances + argmin + gather + STE + loss ----------
__global__ __launch_bounds__(TPB, 4)   // cap 128 VGPR -> 4 waves/EU
void vq_main(const float* __restrict__ x, const float* __restrict__ cb,
             const float* __restrict__ cbT, const float* __restrict__ cb2g,
             float* __restrict__ outq, float* __restrict__ outidx,
             double* __restrict__ lacc)
{
    __shared__ __align__(16) float xs[ND][TM];   // 8 KB
    __shared__ float x2s[TM];
    __shared__ float wbd[4][TM];                 // per-wave best dist
    __shared__ int   wbi[4][TM];
    __shared__ int   fidx[TM];
    __shared__ float redv[4];

    const int tid = threadIdx.x;
    const int blk = blockIdx.x;
    const int b   = blk >> 5;              // 32 batches
    const int hw0 = (blk & 31) * TM;       // 32 tiles of 32 positions
    const float* xb = x + b * (ND * NHW) + hw0;

    // stage x tile (coalesced over m; wave covers 2 d-rows of 128B)
    #pragma unroll
    for (int i = tid; i < ND * TM; i += TPB) {
        int d = i >> 5, m = i & 31;
        xs[d][m] = xb[d * NHW + m];
    }
    __syncthreads();

    // ||x||^2 per position: sequential d, square-then-add (mimic reference)
    if (tid < TM) {
        float s = 0.f;
        #pragma unroll 8
        for (int d = 0; d < ND; ++d) {
            float v = xs[d][tid];
            s = __fadd_rn(s, __fmul_rn(v, v));
        }
        x2s[tid] = s;
    }
    __syncthreads();

    const int mg = tid & 7;      // m-group: positions m0..m0+3
    const int kg = tid >> 3;     // k-group (0..31): k = pass*256 + kg*8 ..+7
    const int m0 = mg * MT;

    float x2loc[MT];
    #pragma unroll
    for (int j = 0; j < MT; ++j) x2loc[j] = x2s[m0 + j];

    float bd[MT];
    int   bi[MT];
    #pragma unroll
    for (int j = 0; j < MT; ++j) { bd[j] = FBIG; bi[j] = 0; }

    for (int pass = 0; pass < NPASS; ++pass) {
        const int k0 = pass * KTILE + kg * KT;
        float acc[MT][KT];
        #pragma unroll
        for (int j = 0; j < MT; ++j)
            #pragma unroll
            for (int jj = 0; jj < KT; ++jj) acc[j][jj] = 0.f;

        const float* bp = cbT + k0;
        #pragma unroll 2
        for (int d = 0; d < ND; ++d) {
            f4 a  = *reinterpret_cast<const f4*>(&xs[d][m0]);      // LDS pipe
            f4 b0 = *reinterpret_cast<const f4*>(&bp[d * NK]);     // L1 pipe
            f4 b1 = *reinterpret_cast<const f4*>(&bp[d * NK + 4]);
            #pragma unroll
            for (int j = 0; j < MT; ++j) {
                float av = a[j];
                #pragma unroll
                for (int jj = 0; jj < KT; ++jj) {
                    float bv = (jj < 4) ? b0[jj & 3] : b1[jj & 3];
                    acc[j][jj] = fmaf(av, bv, acc[j][jj]);         // seq-d fma dot
                }
            }
        }

        // fold distances: dist = fl( fl(x2 + cb2) - 2*dot ), k ascending
        #pragma unroll
        for (int jj = 0; jj < KT; ++jj) {
            const int kgl = k0 + jj;
            const float c2 = cb2g[kgl];
            #pragma unroll
            for (int j = 0; j < MT; ++j) {
                float t    = __fadd_rn(x2loc[j], c2);
                float dist = __fsub_rn(t, 2.0f * acc[j][jj]);      // 2*dot exact
                if (dist < bd[j]) { bd[j] = dist; bi[j] = kgl; }   // strict <: first idx
            }
        }
    }

    // intra-wave reduce over the wave's 8 k-groups (lanes ^8,^16,^32), lexicographic
    #pragma unroll
    for (int off = 8; off <= 32; off <<= 1) {
        #pragma unroll
        for (int j = 0; j < MT; ++j) {
            float od = __shfl_xor(bd[j], off, 64);
            int   oi = __shfl_xor(bi[j], off, 64);
            if (od < bd[j] || (od == bd[j] && oi < bi[j])) { bd[j] = od; bi[j] = oi; }
        }
    }
    const int w = tid >> 6;
    if ((tid & 63) < 8) {
        #pragma unroll
        for (int j = 0; j < MT; ++j) { wbd[w][m0 + j] = bd[j]; wbi[w][m0 + j] = bi[j]; }
    }
    __syncthreads();

    // cross-wave reduce + index write (waves cover ascending k-blocks)
    if (tid < TM) {
        float bestd = wbd[0][tid];
        int   besti = wbi[0][tid];
        #pragma unroll
        for (int t = 1; t < 4; ++t) {
            float dv = wbd[t][tid];
            int   iv = wbi[t][tid];
            if (dv < bestd || (dv == bestd && iv < besti)) { bestd = dv; besti = iv; }
        }
        fidx[tid] = besti;
        outidx[b * NHW + hw0 + tid] = (float)besti;
    }
    __syncthreads();

    // epilogue: gather codebook row, STE out = fl(x + fl(q - x)), loss accum
    const int m  = tid & 31;
    const int cq = tid >> 5;                 // channel octet: 0..7 (8 ch each)
    const int myk = fidx[m];
    const float* crow = cb + myk * ND + cq * 8;
    float* oq = outq + b * (ND * NHW) + hw0 + m + cq * 8 * NHW;
    float ll = 0.f;
    #pragma unroll
    for (int cc = 0; cc < 2; ++cc) {
        f4 v = *reinterpret_cast<const f4*>(&crow[cc * 4]);   // L2-hot gather
        #pragma unroll
        for (int j = 0; j < 4; ++j) {
            int c = cq * 8 + cc * 4 + j;
            float xv = xs[c][m];
            float xd = __fsub_rn(v[j], xv);
            oq[(cc * 4 + j) * NHW] = __fadd_rn(xv, xd);
            ll = fmaf(xd, xd, ll);
        }
    }
    #pragma unroll
    for (int off = 32; off > 0; off >>= 1) ll += __shfl_down(ll, off, 64);
    if ((tid & 63) == 0) redv[tid >> 6] = ll;
    __syncthreads();
    if (tid == 0) {
        double s = (double)redv[0] + (double)redv[1] + (double)redv[2] + (double)redv[3];
        atomicAdd(lacc, s);
    }
}

// ---------- finalize: L = mean((q-x)^2); vq_loss = L + 0.25*L ----------
// e_latent_loss == q_latent_loss numerically (same fp32 inputs/op), so
// vq_loss = L + 0.25*L with the reference's add/mul rounding.
__global__ void vq_fin(const double* __restrict__ lacc, float* __restrict__ outloss) {
    double a = *lacc;
    float L = (float)(a * (1.0 / (double)QELEMS));
    *outloss = __fadd_rn(L, __fmul_rn(0.25f, L));
}

extern "C" void kernel_launch(void* const* d_in, const int* in_sizes, int n_in,
                              void* d_out, int out_size, void* d_ws, size_t ws_size,
                              hipStream_t stream) {
    const float* x  = (const float*)d_in[0];
    const float* cb = (const float*)d_in[1];
    float* outq    = (float*)d_out;
    float* outloss = outq + QELEMS;
    float* outidx  = outq + QELEMS + 1;

    float*  cb2  = (float*)d_ws;                                  // 4 KB slot
    float*  cbT  = (float*)((char*)d_ws + 4096);                  // 256 KB
    double* lacc = (double*)((char*)d_ws + 4096 + NK * ND * 4);   // 8 B

    vq_prep<<<256, 256, 0, stream>>>(cb, cb2, cbT, lacc);
    vq_main<<<NBLK, TPB, 0, stream>>>(x, cb, cbT, cb2, outq, outidx, lacc);
    vq_fin<<<1, 1, 0, stream>>>(lacc, outloss);
}